// Round 1
// baseline (756.183 us; speedup 1.0000x reference)
//
#include <hip/hip_runtime.h>
#include <cstdint>
#include <cstddef>

// Problem constants (B,H,S,Dh) = (2, 8, 2048, 64), all float32.
#define BB 2
#define HH 8
#define SS 2048
#define DD 64

// K1 tiling: each WG = 32 q-rows x all 8 heads x 256 kv positions.
#define QT 32
#define KSPLIT 8
#define KRANGE (SS / KSPLIT)   // 256 kv per WG
#define CKV 64                 // kv chunk per inner iteration

// -------------------- Pass 1: w' = exp(qk/scale + bias) (0 if masked) ------
// Thread map: 256 threads = 8 head-groups of 32 lanes.
// Each thread owns (head hg, kv = kv0+l32 and kv0+l32+32) for the chunk,
// accumulating dot products against 32 q rows held implicitly via global
// (L1-broadcast) q loads.
__global__ __launch_bounds__(256, 3) void sdpa_scores_kernel(
    const float* __restrict__ qg, const float* __restrict__ kg,
    const float* __restrict__ scaleg, const void* __restrict__ maskg,
    const float* __restrict__ biasg, float* __restrict__ outg)
{
  __shared__ unsigned char s_mask[KRANGE];
  __shared__ int s_f32flag, s_u8flag;

  const int t   = (int)threadIdx.x;
  const int bid = (int)blockIdx.x;
  const int b   = bid / ((SS / QT) * KSPLIT);
  const int rem = bid % ((SS / QT) * KSPLIT);
  const int q0     = (rem / KSPLIT) * QT;
  const int kvbase = (rem % KSPLIT) * KRANGE;
  const int hg  = t >> 5;
  const int l32 = t & 31;

  // ---- mask dtype detection (int32 0/1 vs packed bytes vs float 0/1) ----
  if (t == 0) { s_f32flag = 0; s_u8flag = 0; }
  __syncthreads();
  {
    const uint32_t* mw = (const uint32_t*)maskg;
    int f = 0, u = 0;
    for (int i = t; i < 1024; i += 256) {   // 4KB read: safe for all encodings
      uint32_t w = mw[i];
      f |= (w == 0x3F800000u) ? 1 : 0;
      u |= (w > 1u && w != 0x3F800000u) ? 1 : 0;
    }
    if (f) s_f32flag = 1;
    if (u) s_u8flag = 1;
  }
  __syncthreads();
  const int mode = s_f32flag ? 2 : (s_u8flag ? 1 : 0);

  // ---- stage this WG's mask slice (batch b, kv range) into LDS ----
  for (int i = t; i < KRANGE; i += 256) {
    const int gi = b * SS + kvbase + i;
    unsigned char m;
    if (mode == 2)      m = (((const float*)maskg)[gi] != 0.0f) ? 1 : 0;
    else if (mode == 1) m = (((const unsigned char*)maskg)[gi] != 0) ? 1 : 0;
    else                m = (((const int*)maskg)[gi] != 0) ? 1 : 0;
    s_mask[i] = m;
  }
  __syncthreads();

  const float inv_scale = 1.0f / scaleg[0];
  const float* kbase = kg + ((size_t)(b * HH + hg)) * SS * DD;
  const float* qbase = qg + ((size_t)(b * HH + hg)) * SS * DD + (size_t)q0 * DD;
  const float* bbase = biasg + ((size_t)(b * SS + q0)) * SS * HH + hg;
  float*       obase = outg + (((size_t)(b * HH + hg)) * SS + q0) * (size_t)SS;

  for (int kv0 = kvbase; kv0 < kvbase + KRANGE; kv0 += CKV) {
    const int kvA = kv0 + l32;
    const int kvB = kvA + 32;

    float acc0[QT];
    float acc1[QT];
#pragma unroll
    for (int i = 0; i < QT; ++i) { acc0[i] = 0.0f; acc1[i] = 0.0f; }

#pragma unroll 1
    for (int dc = 0; dc < DD; dc += 16) {
      float4 ka[4], kb4[4];
      const float4* kap = (const float4*)(kbase + (size_t)kvA * DD + dc);
      const float4* kbp = (const float4*)(kbase + (size_t)kvB * DD + dc);
#pragma unroll
      for (int j = 0; j < 4; ++j) { ka[j] = kap[j]; kb4[j] = kbp[j]; }

#pragma unroll
      for (int qr = 0; qr < QT; ++qr) {
        const float4* qp = (const float4*)(qbase + (size_t)qr * DD + dc);
        float a0 = acc0[qr], a1 = acc1[qr];
#pragma unroll
        for (int j = 0; j < 4; ++j) {
          const float4 qf = qp[j];
          a0 = fmaf(qf.x, ka[j].x, a0);
          a0 = fmaf(qf.y, ka[j].y, a0);
          a0 = fmaf(qf.z, ka[j].z, a0);
          a0 = fmaf(qf.w, ka[j].w, a0);
          a1 = fmaf(qf.x, kb4[j].x, a1);
          a1 = fmaf(qf.y, kb4[j].y, a1);
          a1 = fmaf(qf.z, kb4[j].z, a1);
          a1 = fmaf(qf.w, kb4[j].w, a1);
        }
        acc0[qr] = a0; acc1[qr] = a1;
      }
    }

    const int mA = s_mask[kvA - kvbase];
    const int mB = s_mask[kvB - kvbase];
#pragma unroll
    for (int qr = 0; qr < QT; ++qr) {
      const float* bp = bbase + ((size_t)qr * SS + kv0) * HH;
      const float sA = fmaf(acc0[qr], inv_scale, bp[(size_t)l32 * HH]);
      const float sB = fmaf(acc1[qr], inv_scale, bp[((size_t)l32 + 32) * HH]);
      const float wA = mA ? 0.0f : __expf(sA);
      const float wB = mB ? 0.0f : __expf(sB);
      obase[(size_t)qr * SS + kvA] = wA;
      obase[(size_t)qr * SS + kvB] = wB;
    }
    __syncthreads();  // keep the 8 head-groups time-aligned for bias L1 reuse
  }
}

// -------------------- Pass 2: per-row normalize (in place) -----------------
// One wave per row of 2048 floats; 4 rows per 256-thread block.
__global__ __launch_bounds__(256, 4) void sdpa_norm_kernel(float* __restrict__ outg)
{
  const int wave = (int)threadIdx.x >> 6;
  const int lane = (int)threadIdx.x & 63;
  const size_t row = (size_t)blockIdx.x * 4 + wave;   // < B*H*S = 32768
  float4* p = (float4*)(outg + row * (size_t)SS);

  float4 v[8];
  float sum = 0.0f;
#pragma unroll
  for (int j = 0; j < 8; ++j) {
    v[j] = p[j * 64 + lane];
    sum += (v[j].x + v[j].y) + (v[j].z + v[j].w);
  }
#pragma unroll
  for (int off = 32; off > 0; off >>= 1) sum += __shfl_xor(sum, off, 64);

  const float inv = (sum > 0.0f) ? (1.0f / sum) : 0.0f;
#pragma unroll
  for (int j = 0; j < 8; ++j) {
    v[j].x *= inv; v[j].y *= inv; v[j].z *= inv; v[j].w *= inv;
    p[j * 64 + lane] = v[j];
  }
}

extern "C" void kernel_launch(void* const* d_in, const int* in_sizes, int n_in,
                              void* d_out, int out_size, void* d_ws, size_t ws_size,
                              hipStream_t stream) {
  const float* qg  = (const float*)d_in[0];
  const float* kg  = (const float*)d_in[1];
  const float* sc  = (const float*)d_in[2];
  const void*  mk  = d_in[3];
  const float* bg  = (const float*)d_in[4];
  float* out = (float*)d_out;

  const int g1 = BB * (SS / QT) * KSPLIT;        // 1024 WGs
  sdpa_scores_kernel<<<dim3(g1), dim3(256), 0, stream>>>(qg, kg, sc, mk, bg, out);

  const int g2 = (BB * HH * SS) / 4;             // 8192 WGs
  sdpa_norm_kernel<<<dim3(g2), dim3(256), 0, stream>>>(out);
}

// Round 2
// 466.529 us; speedup vs baseline: 1.6209x; 1.6209x over previous
//
#include <hip/hip_runtime.h>
#include <cstdint>
#include <cstddef>

// (B,H,S,Dh) = (2, 8, 2048, 64), all float32 in/out.
#define BB 2
#define HH 8
#define SS 2048
#define DD 64
#define KP 128          // bf16 hi|lo concatenated along k-dim
#define QT 32           // q rows per WG (per wave, all 8 heads)
#define KSPLIT 8
#define KRANGE (SS / KSPLIT)   // 256 kv per WG
#define CKV 64                 // kv chunk per inner iteration
#define NROWS (BB * HH * SS)   // 32768

typedef short short8 __attribute__((ext_vector_type(8)));
typedef float f32x4  __attribute__((ext_vector_type(4)));
using u16 = unsigned short;
using u32 = unsigned int;

__device__ inline u16 bf16_rne(float f) {
  u32 u = __builtin_bit_cast(u32, f);
  u32 r = (u + 0x7FFFu + ((u >> 16) & 1u)) >> 16;
  return (u16)r;
}
__device__ inline float bf16_to_f(u16 h) {
  u32 u = ((u32)h) << 16;
  return __builtin_bit_cast(float, u);
}

// ---------------- K0: f32 -> bf16 hi|lo (K=64 -> K=128) --------------------
// One thread per float4 (handles both q and k). 524288 threads.
__global__ __launch_bounds__(256) void convert_kernel(
    const float* __restrict__ q, const float* __restrict__ k,
    u16* __restrict__ qw, u16* __restrict__ kw)
{
  const int i   = (int)(blockIdx.x * 256 + threadIdx.x);  // float4 index
  const int row = i >> 4;                                  // 16 float4 per row
  const int c4  = (i & 15) << 2;                           // float col in row

  const float4 qv = *(const float4*)(q + (size_t)i * 4);
  const float4 kv = *(const float4*)(k + (size_t)i * 4);

  u16 qh[4], ql[4], kh[4], kl[4];
  {
    const float qa[4] = {qv.x, qv.y, qv.z, qv.w};
    const float ka[4] = {kv.x, kv.y, kv.z, kv.w};
#pragma unroll
    for (int j = 0; j < 4; ++j) {
      qh[j] = bf16_rne(qa[j]);
      ql[j] = bf16_rne(qa[j] - bf16_to_f(qh[j]));
      kh[j] = bf16_rne(ka[j]);
      kl[j] = bf16_rne(ka[j] - bf16_to_f(kh[j]));
    }
  }
  uint2 qhi, qlo, khi, klo;
  qhi.x = (u32)qh[0] | ((u32)qh[1] << 16); qhi.y = (u32)qh[2] | ((u32)qh[3] << 16);
  qlo.x = (u32)ql[0] | ((u32)ql[1] << 16); qlo.y = (u32)ql[2] | ((u32)ql[3] << 16);
  khi.x = (u32)kh[0] | ((u32)kh[1] << 16); khi.y = (u32)kh[2] | ((u32)kh[3] << 16);
  klo.x = (u32)kl[0] | ((u32)kl[1] << 16); klo.y = (u32)kl[2] | ((u32)kl[3] << 16);

  const size_t base = (size_t)row * KP + c4;
  *(uint2*)(qw + base)      = qhi;
  *(uint2*)(qw + base + DD) = qlo;
  *(uint2*)(kw + base)      = khi;
  *(uint2*)(kw + base + DD) = klo;
}

// ---------------- K1: MFMA scores + bias + exp -----------------------------
// PHASE 0: accumulate row sums of w' = exp(qk/scale + bias) (0 if masked)
//          into sums[ksplit][row] (no atomics; each WG owns its slice).
// PHASE 1: recompute w' and write w'/rowsum to out.
// WG = 512 threads = 8 waves = 8 heads, same (b, q-tile, kv-range).
template<int PHASE>
__global__ __launch_bounds__(512, 4) void attn_kernel(
    const u16* __restrict__ qw, const u16* __restrict__ kw,
    const float* __restrict__ scaleg, const void* __restrict__ maskg,
    const float* __restrict__ biasg, float* __restrict__ sums,
    float* __restrict__ outg)
{
  __shared__ unsigned char s_mask[KRANGE];
  __shared__ int s_f32flag, s_u8flag;

  const int t    = (int)threadIdx.x;
  const int h    = t >> 6;        // wave = head
  const int lane = t & 63;
  const int l15  = lane & 15;
  const int l4   = lane >> 4;

  const int bid = (int)blockIdx.x;
  const int b   = bid / ((SS / QT) * KSPLIT);
  const int rem = bid % ((SS / QT) * KSPLIT);
  const int q0     = (rem / KSPLIT) * QT;
  const int ks     = rem % KSPLIT;
  const int kvbase = ks * KRANGE;

  // ---- mask dtype detection (int32 0/1 | packed bytes | float 0/1) ----
  if (t == 0) { s_f32flag = 0; s_u8flag = 0; }
  __syncthreads();
  {
    const u32* mw = (const u32*)maskg;
    int f = 0, u = 0;
    for (int i = t; i < 1024; i += 512) {
      u32 w = mw[i];
      f |= (w == 0x3F800000u) ? 1 : 0;
      u |= (w > 1u && w != 0x3F800000u) ? 1 : 0;
    }
    if (f) s_f32flag = 1;
    if (u) s_u8flag = 1;
  }
  __syncthreads();
  const int mode = s_f32flag ? 2 : (s_u8flag ? 1 : 0);

  for (int i = t; i < KRANGE; i += 512) {
    const int gi = b * SS + kvbase + i;
    unsigned char m;
    if (mode == 2)      m = (((const float*)maskg)[gi] != 0.0f) ? 1 : 0;
    else if (mode == 1) m = (((const unsigned char*)maskg)[gi] != 0) ? 1 : 0;
    else                m = (((const int*)maskg)[gi] != 0) ? 1 : 0;
    s_mask[i] = m;
  }
  __syncthreads();

  const float inv_scale = 1.0f / scaleg[0];
  const size_t bh = (size_t)(b * HH + h);

  // ---- load Q fragments once (rows q0..q0+31, k = 0..127) ----
  short8 afr[2][4];
#pragma unroll
  for (int mi = 0; mi < 2; ++mi)
#pragma unroll
    for (int kf = 0; kf < 4; ++kf) {
      const int row = q0 + mi * 16 + l15;
      afr[mi][kf] = *(const short8*)(qw + (bh * SS + row) * KP + kf * 32 + (l4 << 3));
    }

  // precomputed per-lane row byte offsets
  u32 brow[2][4];   // bias: ((b*S+row)*S)*32 + h*4
  u32 orow[2][4];   // out : ((bh*S)+row)*S*4
#pragma unroll
  for (int mi = 0; mi < 2; ++mi)
#pragma unroll
    for (int j = 0; j < 4; ++j) {
      const int row = q0 + mi * 16 + (l4 << 2) + j;
      brow[mi][j] = (u32)(b * SS + row) * (u32)(SS * 32) + (u32)(h * 4);
      orow[mi][j] = (u32)((b * HH + h) * SS + row) * (u32)(SS * 4);
    }

  float rowsum[2][4];
  float inv_row[2][4];
#pragma unroll
  for (int mi = 0; mi < 2; ++mi)
#pragma unroll
    for (int j = 0; j < 4; ++j) rowsum[mi][j] = 0.0f;

  if (PHASE == 1) {
#pragma unroll
    for (int mi = 0; mi < 2; ++mi)
#pragma unroll
      for (int j = 0; j < 4; ++j) {
        const int row = q0 + mi * 16 + (l4 << 2) + j;
        const size_t idx = bh * SS + row;
        float s = 0.0f;
#pragma unroll
        for (int p = 0; p < KSPLIT; ++p) s += sums[(size_t)p * NROWS + idx];
        inv_row[mi][j] = 1.0f / s;
      }
  }

  // ---- kv chunks of 64 ----
  for (int c = 0; c < KRANGE / CKV; ++c) {
    const int kv0c = kvbase + c * CKV;

    f32x4 acc[2][4];
#pragma unroll
    for (int mi = 0; mi < 2; ++mi)
#pragma unroll
      for (int ni = 0; ni < 4; ++ni) {
        f32x4 z = {0.f, 0.f, 0.f, 0.f};
        acc[mi][ni] = z;
      }

#pragma unroll
    for (int kf = 0; kf < 4; ++kf) {
      short8 bfr[4];
#pragma unroll
      for (int ni = 0; ni < 4; ++ni) {
        const int col = kv0c + ni * 16 + l15;
        bfr[ni] = *(const short8*)(kw + (bh * SS + col) * KP + kf * 32 + (l4 << 3));
      }
#pragma unroll
      for (int mi = 0; mi < 2; ++mi)
#pragma unroll
        for (int ni = 0; ni < 4; ++ni)
          acc[mi][ni] = __builtin_amdgcn_mfma_f32_16x16x32_bf16(
              afr[mi][kf], bfr[ni], acc[mi][ni], 0, 0, 0);
    }

    // epilogue: bias + exp (+ mask), then sum or write
#pragma unroll
    for (int ni = 0; ni < 4; ++ni) {
      const int colL = (kv0c - kvbase) + ni * 16 + l15;
      const float mz = s_mask[colL] ? 0.0f : 1.0f;
      const u32 colb = (u32)(kvbase + colL);
#pragma unroll
      for (int mi = 0; mi < 2; ++mi)
#pragma unroll
        for (int j = 0; j < 4; ++j) {
          const float bv = *(const float*)((const char*)biasg + brow[mi][j] + colb * 32u);
          const float s  = fmaf(acc[mi][ni][j], inv_scale, bv);
          const float w  = mz * __expf(s);
          if (PHASE == 0) {
            rowsum[mi][j] += w;
          } else {
            *(float*)((char*)outg + orow[mi][j] + colb * 4u) = w * inv_row[mi][j];
          }
        }
    }
  }

  if (PHASE == 0) {
#pragma unroll
    for (int mi = 0; mi < 2; ++mi)
#pragma unroll
      for (int j = 0; j < 4; ++j) {
        float v = rowsum[mi][j];
        v += __shfl_xor(v, 1, 64);
        v += __shfl_xor(v, 2, 64);
        v += __shfl_xor(v, 4, 64);
        v += __shfl_xor(v, 8, 64);
        if (l15 == 0) {
          const int row = q0 + mi * 16 + (l4 << 2) + j;
          sums[(size_t)ks * NROWS + bh * SS + row] = v;
        }
      }
  }
}

extern "C" void kernel_launch(void* const* d_in, const int* in_sizes, int n_in,
                              void* d_out, int out_size, void* d_ws, size_t ws_size,
                              hipStream_t stream) {
  const float* qg = (const float*)d_in[0];
  const float* kg = (const float*)d_in[1];
  const float* sc = (const float*)d_in[2];
  const void*  mk = d_in[3];
  const float* bg = (const float*)d_in[4];
  float* out = (float*)d_out;

  // workspace layout: qw (8MB) | kw (8MB) | sums (1MB)
  u16*   qw   = (u16*)d_ws;
  u16*   kw   = qw + (size_t)NROWS * KP;
  float* sums = (float*)(kw + (size_t)NROWS * KP);

  convert_kernel<<<dim3((NROWS * DD / 4) / 256), dim3(256), 0, stream>>>(qg, kg, qw, kw);

  const int g1 = BB * (SS / QT) * KSPLIT;  // 1024 WGs
  attn_kernel<0><<<dim3(g1), dim3(512), 0, stream>>>(qw, kw, sc, mk, bg, sums, out);
  attn_kernel<1><<<dim3(g1), dim3(512), 0, stream>>>(qw, kw, sc, mk, bg, sums, out);
}

// Round 3
// 276.245 us; speedup vs baseline: 2.7374x; 1.6888x over previous
//
#include <hip/hip_runtime.h>
#include <cstdint>
#include <cstddef>

// (B,H,S,Dh) = (2, 8, 2048, 64), all float32 in/out.
#define BB 2
#define HH 8
#define SS 2048
#define DD 64
#define KP 128          // bf16 hi|lo concatenated along k-dim
#define QT 32           // q rows per WG (per wave, all 8 heads)
#define KSPLIT 8
#define KRANGE (SS / KSPLIT)   // 256 kv per WG
#define CKV 32                 // kv chunk per inner iteration (LDS-staged bias)
#define NCHUNK (KRANGE / CKV)  // 8
#define NROWS (BB * HH * SS)   // 32768

typedef short short8 __attribute__((ext_vector_type(8)));
typedef float f32x4  __attribute__((ext_vector_type(4)));
using u16 = unsigned short;
using u32 = unsigned int;

__device__ inline u16 bf16_rne(float f) {
  u32 u = __builtin_bit_cast(u32, f);
  u32 r = (u + 0x7FFFu + ((u >> 16) & 1u)) >> 16;
  return (u16)r;
}
__device__ inline float bf16_to_f(u16 h) {
  u32 u = ((u32)h) << 16;
  return __builtin_bit_cast(float, u);
}

// ---------------- K0: f32 -> bf16 hi|lo (K=64 -> K=128) --------------------
__global__ __launch_bounds__(256) void convert_kernel(
    const float* __restrict__ q, const float* __restrict__ k,
    u16* __restrict__ qw, u16* __restrict__ kw)
{
  const int i   = (int)(blockIdx.x * 256 + threadIdx.x);  // float4 index
  const int row = i >> 4;
  const int c4  = (i & 15) << 2;

  const float4 qv = *(const float4*)(q + (size_t)i * 4);
  const float4 kv = *(const float4*)(k + (size_t)i * 4);

  u16 qh[4], ql[4], kh[4], kl[4];
  {
    const float qa[4] = {qv.x, qv.y, qv.z, qv.w};
    const float ka[4] = {kv.x, kv.y, kv.z, kv.w};
#pragma unroll
    for (int j = 0; j < 4; ++j) {
      qh[j] = bf16_rne(qa[j]);
      ql[j] = bf16_rne(qa[j] - bf16_to_f(qh[j]));
      kh[j] = bf16_rne(ka[j]);
      kl[j] = bf16_rne(ka[j] - bf16_to_f(kh[j]));
    }
  }
  uint2 qhi, qlo, khi, klo;
  qhi.x = (u32)qh[0] | ((u32)qh[1] << 16); qhi.y = (u32)qh[2] | ((u32)qh[3] << 16);
  qlo.x = (u32)ql[0] | ((u32)ql[1] << 16); qlo.y = (u32)ql[2] | ((u32)ql[3] << 16);
  khi.x = (u32)kh[0] | ((u32)kh[1] << 16); khi.y = (u32)kh[2] | ((u32)kh[3] << 16);
  klo.x = (u32)kl[0] | ((u32)kl[1] << 16); klo.y = (u32)kl[2] | ((u32)kl[3] << 16);

  const size_t base = (size_t)row * KP + c4;
  *(uint2*)(qw + base)      = qhi;
  *(uint2*)(qw + base + DD) = qlo;
  *(uint2*)(kw + base)      = khi;
  *(uint2*)(kw + base + DD) = klo;
}

// ---------------- K1: MFMA scores + bias + exp -----------------------------
// WG = 512 threads = 8 waves = 8 heads, same (b, q-tile 32, kv-range 256).
// Bias staged per 32-kv chunk through LDS: global float4 coalesced reads ->
// transpose to [h][qrow][kv^swz] (2-way banks only), waves read own h-plane.
// PHASE 0: accumulate partial row sums of w' = exp(qk/scale+bias) (0 masked).
// PHASE 1: recompute w' and write w'/rowsum.
template<int PHASE>
__global__ __launch_bounds__(512, 4) void attn_kernel(
    const u16* __restrict__ qw, const u16* __restrict__ kw,
    const float* __restrict__ scaleg, const void* __restrict__ maskg,
    const float* __restrict__ biasg, float* __restrict__ sums,
    float* __restrict__ outg)
{
  __shared__ float s_bias[HH * QT * CKV];   // 32 KB: [h][qr][kv']
  __shared__ unsigned char s_mask[KRANGE];
  __shared__ int s_f32flag, s_u8flag;

  const int t    = (int)threadIdx.x;
  const int wid  = t >> 6;        // wave = head
  const int lane = t & 63;
  const int l15  = lane & 15;
  const int l4   = lane >> 4;

  const int bid = (int)blockIdx.x;
  const int b   = bid / ((SS / QT) * KSPLIT);
  const int rem = bid % ((SS / QT) * KSPLIT);
  const int q0     = (rem / KSPLIT) * QT;
  const int ks     = rem % KSPLIT;
  const int kvbase = ks * KRANGE;

  // ---- mask dtype detection (int32 0/1 | packed bytes | float 0/1) ----
  if (t == 0) { s_f32flag = 0; s_u8flag = 0; }
  __syncthreads();
  {
    const u32* mw = (const u32*)maskg;
    int f = 0, u = 0;
    for (int i = t; i < 1024; i += 512) {
      u32 w = mw[i];
      f |= (w == 0x3F800000u) ? 1 : 0;
      u |= (w > 1u && w != 0x3F800000u) ? 1 : 0;
    }
    if (f) s_f32flag = 1;
    if (u) s_u8flag = 1;
  }
  __syncthreads();
  const int mode = s_f32flag ? 2 : (s_u8flag ? 1 : 0);

  for (int i = t; i < KRANGE; i += 512) {
    const int gi = b * SS + kvbase + i;
    unsigned char m;
    if (mode == 2)      m = (((const float*)maskg)[gi] != 0.0f) ? 1 : 0;
    else if (mode == 1) m = (((const unsigned char*)maskg)[gi] != 0) ? 1 : 0;
    else                m = (((const int*)maskg)[gi] != 0) ? 1 : 0;
    s_mask[i] = m;
  }

  const float inv_scale = 1.0f / scaleg[0];
  const size_t bh = (size_t)(b * HH + wid);

  // ---- Q fragments (rows q0..q0+31, k = 0..127), hoisted ----
  short8 afr[2][4];
#pragma unroll
  for (int mi = 0; mi < 2; ++mi)
#pragma unroll
    for (int kf = 0; kf < 4; ++kf) {
      const int row = q0 + mi * 16 + l15;
      afr[mi][kf] = *(const short8*)(qw + (bh * SS + row) * KP + kf * 32 + (l4 << 3));
    }

  // ---- bias staging thread constants ----
  // thread t stages rows qr = r*8 + wid (r=0..3), kv = kvL_st.., heads hh*4..+3
  const int kvL_st = lane >> 1;
  const int hh     = lane & 1;
  const int swz_st = ((wid >> 2) & 1) << 4;          // = ((qr>>2)&1)<<4 for qr=r*8+wid
  const int kvl2_st = kvL_st ^ swz_st;
  const float* bsrc0 = biasg +
      (((size_t)(b * SS + q0 + wid)) * SS + kvbase + kvL_st) * HH + hh * 4;
  float* sdst0 = &s_bias[(hh * 4) * (QT * CKV) + wid * CKV + kvl2_st];
  const size_t bstep_r = (size_t)8 * SS * HH;        // +8 q-rows

  float4 pre[4];
#pragma unroll
  for (int r = 0; r < 4; ++r)
    pre[r] = *(const float4*)(bsrc0 + (size_t)r * bstep_r);

  float rowsum[2][4];
  float inv_row[2][4];
#pragma unroll
  for (int mi = 0; mi < 2; ++mi)
#pragma unroll
    for (int j = 0; j < 4; ++j) rowsum[mi][j] = 0.0f;

  if (PHASE == 1) {
#pragma unroll
    for (int mi = 0; mi < 2; ++mi)
#pragma unroll
      for (int j = 0; j < 4; ++j) {
        const int row = q0 + mi * 16 + (l4 << 2) + j;
        const size_t idx = bh * SS + row;
        float s = 0.0f;
#pragma unroll
        for (int p = 0; p < KSPLIT; ++p) s += sums[(size_t)p * NROWS + idx];
        inv_row[mi][j] = (s > 0.0f) ? (1.0f / s) : 0.0f;
      }
  }

  for (int c = 0; c < NCHUNK; ++c) {
    const int kv0c = kvbase + c * CKV;

    __syncthreads();   // readers of previous chunk done (also covers s_mask)
#pragma unroll
    for (int r = 0; r < 4; ++r) {
      float* d = sdst0 + r * (8 * CKV);
      d[0]             = pre[r].x;
      d[QT * CKV]      = pre[r].y;
      d[2 * QT * CKV]  = pre[r].z;
      d[3 * QT * CKV]  = pre[r].w;
    }
    __syncthreads();   // chunk c bias visible

    if (c + 1 < NCHUNK) {
#pragma unroll
      for (int r = 0; r < 4; ++r)
        pre[r] = *(const float4*)(bsrc0 + (size_t)r * bstep_r +
                                  (size_t)(c + 1) * (CKV * HH));
    }

    f32x4 acc[2][2];
#pragma unroll
    for (int mi = 0; mi < 2; ++mi)
#pragma unroll
      for (int ni = 0; ni < 2; ++ni) {
        f32x4 z = {0.f, 0.f, 0.f, 0.f};
        acc[mi][ni] = z;
      }

#pragma unroll
    for (int kf = 0; kf < 4; ++kf) {
      short8 bfr[2];
#pragma unroll
      for (int ni = 0; ni < 2; ++ni) {
        const int col = kv0c + ni * 16 + l15;
        bfr[ni] = *(const short8*)(kw + (bh * SS + col) * KP + kf * 32 + (l4 << 3));
      }
#pragma unroll
      for (int mi = 0; mi < 2; ++mi)
#pragma unroll
        for (int ni = 0; ni < 2; ++ni)
          acc[mi][ni] = __builtin_amdgcn_mfma_f32_16x16x32_bf16(
              afr[mi][kf], bfr[ni], acc[mi][ni], 0, 0, 0);
    }

    // epilogue: bias(LDS) + exp (+ mask), then sum or write
#pragma unroll
    for (int ni = 0; ni < 2; ++ni) {
      const int kvLloc = ni * 16 + l15;
      const float mz = s_mask[c * CKV + kvLloc] ? 0.0f : 1.0f;
      const int bidx = wid * (QT * CKV) + (kvLloc ^ ((l4 & 1) << 4));
      const u32 colb = (u32)(kv0c + kvLloc);
#pragma unroll
      for (int mi = 0; mi < 2; ++mi)
#pragma unroll
        for (int j = 0; j < 4; ++j) {
          const int qrl = mi * 16 + (l4 << 2) + j;
          const float bv = s_bias[bidx + qrl * CKV];
          const float s  = fmaf(acc[mi][ni][j], inv_scale, bv);
          const float w  = mz * __expf(s);
          if (PHASE == 0) {
            rowsum[mi][j] += w;
          } else {
            const size_t o = (bh * SS + (size_t)(q0 + qrl)) * SS + colb;
            outg[o] = w * inv_row[mi][j];
          }
        }
    }
  }

  if (PHASE == 0) {
#pragma unroll
    for (int mi = 0; mi < 2; ++mi)
#pragma unroll
      for (int j = 0; j < 4; ++j) {
        float v = rowsum[mi][j];
        v += __shfl_xor(v, 1, 64);
        v += __shfl_xor(v, 2, 64);
        v += __shfl_xor(v, 4, 64);
        v += __shfl_xor(v, 8, 64);
        if (l15 == 0) {
          const int row = q0 + mi * 16 + (l4 << 2) + j;
          sums[(size_t)ks * NROWS + bh * SS + row] = v;
        }
      }
  }
}

extern "C" void kernel_launch(void* const* d_in, const int* in_sizes, int n_in,
                              void* d_out, int out_size, void* d_ws, size_t ws_size,
                              hipStream_t stream) {
  const float* qg = (const float*)d_in[0];
  const float* kg = (const float*)d_in[1];
  const float* sc = (const float*)d_in[2];
  const void*  mk = d_in[3];
  const float* bg = (const float*)d_in[4];
  float* out = (float*)d_out;

  // workspace: qw (8MB) | kw (8MB) | sums (1MB)
  u16*   qw   = (u16*)d_ws;
  u16*   kw   = qw + (size_t)NROWS * KP;
  float* sums = (float*)(kw + (size_t)NROWS * KP);

  convert_kernel<<<dim3((NROWS * DD / 4) / 256), dim3(256), 0, stream>>>(qg, kg, qw, kw);

  const int g1 = BB * (SS / QT) * KSPLIT;  // 1024 WGs
  attn_kernel<0><<<dim3(g1), dim3(512), 0, stream>>>(qw, kw, sc, mk, bg, sums, out);
  attn_kernel<1><<<dim3(g1), dim3(512), 0, stream>>>(qw, kw, sc, mk, bg, sums, out);
}